// Round 11
// baseline (320.394 us; speedup 1.0000x reference)
//
#include <hip/hip_runtime.h>
#include <hip/hip_cooperative_groups.h>
namespace cg = cooperative_groups;

#define DIM     128
#define NCODES  1024
#define TILE_M  64
#define FLAGThr 0.018f       // acc-units: fp16 Hoeffding 0.010 + 2x pack err 0.008
#define RPB     4            // fallback refine rows per block
#define RPBF    8            // fused refine rows per block
#define FGRID   512          // fused grid (2 blocks/CU x 256 CU, exactly resident)

typedef __attribute__((ext_vector_type(8))) _Float16 half8;
typedef __attribute__((ext_vector_type(4))) _Float16 half4;
typedef __attribute__((ext_vector_type(4))) float    f32x4;

#define AS1 __attribute__((address_space(1)))
#define AS3 __attribute__((address_space(3)))

// ws layout:
//      0 : e2d    (1024 double)          8 KB
//   8192 : e2f    (1024 float)           4 KB
//  12288 : eh     (1024*128 _Float16)  256 KB
// 274432 : embedT (128*1024 float)     512 KB
// 798720 : cnt    (int)
// 798976 : list   (65536 int)          256 KB

// ============================ FUSED (v14) ==================================
// r10 post-mortem: pass1 at its concurrency plateau (v11 12w x depth2 ==
// v13 8w x depth3 == 96KB in-flight/CU -> 45-47us both). Kernel sum ~65us
// vs total 134.5 -> ~70us is inter-kernel serialization/launch/cold-start.
// v14: one cooperative kernel, grid 512 x 256 (exactly resident: LDS
// 67.25KB x2 <= 160KB, (256,2) regs).
//   phase 0: blocks 0-15 do setup WHILE all blocks load x-tile (overlap)
//   grid.sync()
//   phase 1: v13 pass1 pipeline (wave-private DMA, counted vmcnt, swizzle
//            involution, zero loop barriers) for tiles bid and bid+512
//   grid.sync()
//   phase 2: refine, RPB=8 (halves embedT sweeps), grid-stride
// LDS phase-overlaid in one 68864-B arena. Host falls back to the 3-launch
// v13 path if cooperative launch is refused.
__global__ __launch_bounds__(256, 2) void fused_kernel(
    const float* __restrict__ x, const float* __restrict__ embed,
    double* __restrict__ e2d, float* __restrict__ e2f,
    _Float16* __restrict__ eh, float* __restrict__ embedT,
    float* __restrict__ outQ, float* __restrict__ outIdx,
    int* __restrict__ cnt, int* __restrict__ list)
{
  // arena:
  // [0,17408)      xh fp16[64][136]         | phase2: xsf f32[128][8] (4KB)
  // [17408,66560)  bbuf[4][3][4096]         | phase0: setup tile+psum
  //                                         | phase2: rb1/rb2/ri1/ri2/cand
  // [66560,67584)  rb_best[4][64] f32
  // [67584,68608)  rb_sec [4][64] f32
  // [68608,68864)  fidx[64] int
  __shared__ __align__(16) unsigned char smem[68864];
  _Float16* xh = (_Float16*)smem;
  float (*rb_best)[TILE_M] = (float (*)[TILE_M])(smem + 66560);
  float (*rb_sec )[TILE_M] = (float (*)[TILE_M])(smem + 67584);
  int*   fidx              = (int*)(smem + 68608);

  const int tid = threadIdx.x, bid = blockIdx.x;
  const int l = tid & 63, w = tid >> 6;
  const int rl = l & 15,  q = l >> 4;

  // ---------------- phase 0: setup (bid<16) + x(tile0) all blocks ----------
  if (bid == 0 && tid == 0) *cnt = 0;

  {
    const f32x4* x4 = (const f32x4*)(x + (size_t)bid * TILE_M * DIM);
    #pragma unroll
    for (int i = 0; i < 8; ++i) {
      int e = tid + i * 256;                 // 2048 float4s = 64x128
      int r = e >> 5, c4 = e & 31;
      f32x4 v = x4[e];
      half4 h;
      h[0] = (_Float16)v[0]; h[1] = (_Float16)v[1];
      h[2] = (_Float16)v[2]; h[3] = (_Float16)v[3];
      *(half4*)&xh[r * 136 + c4 * 4] = h;
    }
  }

  if (bid < 16) {                            // setup role (overlays bbuf region)
    float  (*tile)[132] = (float  (*)[132])(smem + 17408);  // 33792 B
    double (*psum)[64]  = (double (*)[64]) (smem + 51200);  //  2048 B
    const int c0 = bid * 64;
    const f32x4* E4 = (const f32x4*)(embed + (size_t)c0 * DIM);
    #pragma unroll
    for (int i = 0; i < 8; ++i) {
      int e = tid + i * 256;
      int r = e >> 5, c4 = e & 31;
      f32x4 v = E4[e];
      *(f32x4*)&tile[r][c4 * 4] = v;
      half4 h;
      h[0] = (_Float16)v[0]; h[1] = (_Float16)v[1];
      h[2] = (_Float16)v[2]; h[3] = (_Float16)v[3];
      *(half4*)&eh[(size_t)(c0 + r) * DIM + c4 * 4] = h;
    }
    __syncthreads();
    {
      int r = tid & 63, part = tid >> 6;
      double s = 0.0;
      #pragma unroll
      for (int k = 0; k < 32; ++k) {
        float v = tile[r][part * 32 + k];
        s += (double)v * v;
      }
      psum[part][r] = s;
    }
    __syncthreads();
    if (tid < 64) {
      double s = psum[0][tid] + psum[1][tid] + psum[2][tid] + psum[3][tid];
      e2d[c0 + tid] = s;
      e2f[c0 + tid] = (float)s;
    }
    #pragma unroll
    for (int i = 0; i < 32; ++i) {
      int idx = tid + i * 256;               // 8192 = 128k x 64c
      int k = idx >> 6, c = idx & 63;
      embedT[(size_t)k * NCODES + c0 + c] = tile[c][k];
    }
  }

  cg::this_grid().sync();                    // eh/e2f/embedT visible grid-wide

  // ---------------- phase 1: pass1 for tiles bid and bid+512 ---------------
#define STAGE_W(CH)                                                           \
  {                                                                           \
    const char* ebase = (const char*)eh + ((size_t)(CH) * 64 + w * 16) * 256; \
    unsigned char* buf = smem + 17408 + (w * 3 + (CH) % 3) * 4096;            \
    _Pragma("unroll")                                                         \
    for (int j = 0; j < 4; ++j) {                                             \
      int u  = j * 64 + l;                  /* 16B-unit 0..255 = 16r x 16c */ \
      int rr = u >> 4, cc = u & 15;                                           \
      const char* src = ebase + rr * 256 + ((cc ^ rr) * 16);                  \
      __builtin_amdgcn_global_load_lds(                                       \
          (AS1 void*)src,                                                     \
          (AS3 void*)(buf + j * 1024), 16, 0, 0);                             \
    }                                                                         \
  }

  float vin[16];                             // code(ch) = ch*64 + w*16 + rl
  #pragma unroll
  for (int g = 0; g < 16; ++g)
    vin[g] = fmaf(-0.5f, e2f[g * 64 + w * 16 + rl], -16.0f);
  asm volatile("s_waitcnt vmcnt(0)" ::: "memory");  // vin retired: clean count
  __builtin_amdgcn_sched_barrier(0);

  for (int tt = 0; tt < 2; ++tt) {
    const int row0 = (bid + tt * FGRID) * TILE_M;
    if (tt) {
      __syncthreads();                       // prev tile fully done with xh
      const f32x4* x4 = (const f32x4*)(x + (size_t)row0 * DIM);
      #pragma unroll
      for (int i = 0; i < 8; ++i) {
        int e = tid + i * 256;
        int r = e >> 5, c4 = e & 31;
        f32x4 v = x4[e];
        half4 h;
        h[0] = (_Float16)v[0]; h[1] = (_Float16)v[1];
        h[2] = (_Float16)v[2]; h[3] = (_Float16)v[3];
        *(half4*)&xh[r * 136 + c4 * 4] = h;
      }
    }
    __syncthreads();                         // xh visible; vmcnt drained

    half8 afrag[4][4];
    #pragma unroll
    for (int m = 0; m < 4; ++m)
      #pragma unroll
      for (int ks = 0; ks < 4; ++ks)
        afrag[m][ks] = *(const half8*)&xh[(m * 16 + rl) * 136 + ks * 32 + q * 8];

    float bestp[16], secp[16];
    #pragma unroll
    for (int s = 0; s < 16; ++s) { bestp[s] = -3.0e38f; secp[s] = -3.3e38f; }

    STAGE_W(0)
    STAGE_W(1)
    STAGE_W(2)

    #pragma unroll
    for (int ch = 0; ch < 16; ++ch) {
      if (ch <= 13) {
        asm volatile("s_waitcnt vmcnt(8)" ::: "memory");
      } else if (ch == 14) {
        asm volatile("s_waitcnt vmcnt(4)" ::: "memory");
      } else {
        asm volatile("s_waitcnt vmcnt(0)" ::: "memory");
      }
      __builtin_amdgcn_sched_barrier(0);

      const unsigned char* bb = smem + 17408 + (w * 3 + ch % 3) * 4096;
      half8 bfrag[4];
      #pragma unroll
      for (int ks = 0; ks < 4; ++ks)
        bfrag[ks] = *(const half8*)(bb + rl * 256 + (((ks * 4 + q) ^ rl) * 16));

      const float vinit = vin[ch];
      const int mycode = ch * 64 + w * 16 + rl;
      #pragma unroll
      for (int m = 0; m < 4; ++m) {
        f32x4 acc = (f32x4){vinit, vinit, vinit, vinit};
        #pragma unroll
        for (int ks = 0; ks < 4; ++ks)
          acc = __builtin_amdgcn_mfma_f32_16x16x32_f16(afrag[m][ks], bfrag[ks], acc, 0, 0, 0);
        #pragma unroll
        for (int r = 0; r < 4; ++r) {
          const int s = m * 4 + r;
          float scp = __int_as_float((__float_as_int(acc[r]) & ~1023) | mycode);
          secp[s]  = __builtin_amdgcn_fmed3f(scp, bestp[s], secp[s]);
          bestp[s] = fmaxf(bestp[s], scp);
        }
      }

      if (ch + 3 < 16) {
        asm volatile("s_waitcnt lgkmcnt(0)" ::: "memory");
        __builtin_amdgcn_sched_barrier(0);
        STAGE_W(ch + 3)
      }
    }

    // merge across the 16 lanes of each quarter
    #pragma unroll
    for (int off = 1; off < 16; off <<= 1) {
      #pragma unroll
      for (int s = 0; s < 16; ++s) {
        float ob = __shfl_xor(bestp[s], off, 16);
        float os = __shfl_xor(secp[s],  off, 16);
        secp[s]  = fmaxf(__builtin_amdgcn_fmed3f(bestp[s], ob, secp[s]), os);
        bestp[s] = fmaxf(bestp[s], ob);
      }
    }
    if (rl == 0) {
      #pragma unroll
      for (int m = 0; m < 4; ++m)
        #pragma unroll
        for (int r = 0; r < 4; ++r) {
          int s = m * 4 + r;
          int row = m * 16 + q * 4 + r;
          rb_best[w][row] = bestp[s];
          rb_sec [w][row] = secp[s];
        }
    }
    __syncthreads();

    if (tid < TILE_M) {
      float bv = rb_best[0][tid], sv = rb_sec[0][tid];
      #pragma unroll
      for (int ww = 1; ww < 4; ++ww) {
        float ob = rb_best[ww][tid], os = rb_sec[ww][tid];
        sv = fmaxf(__builtin_amdgcn_fmed3f(bv, ob, sv), os);
        bv = fmaxf(bv, ob);
      }
      int bi = __float_as_int(bv) & 1023;
      int grow = row0 + tid;
      outIdx[grow] = (float)bi;
      fidx[tid] = bi;
      if (bv - sv <= FLAGThr) {
        int p = atomicAdd(cnt, 1);
        list[p] = grow;
      }
    }
    __syncthreads();

    {
      const f32x4* E4   = (const f32x4*)embed;
      f32x4*       out4 = (f32x4*)(outQ + (size_t)row0 * DIM);
      #pragma unroll
      for (int i = 0; i < 8; ++i) {
        int e = tid + i * 256;
        int r = e >> 5, c4 = e & 31;
        out4[e] = E4[fidx[r] * 32 + c4];
      }
    }
  }
#undef STAGE_W

  cg::this_grid().sync();                    // cnt/list complete

  // ---------------- phase 2: refine, RPB=8, grid-stride 512 ----------------
  {
    const int n = *cnt;
    float* xsf = (float*)smem;               // [128][8] f32 (4 KB, over xh)
    float (*rb1)[4]  = (float (*)[4])(smem + 17408);
    float (*rb2)[4]  = (float (*)[4])(smem + 17536);
    int   (*ri1)[4]  = (int   (*)[4])(smem + 17664);
    int   (*ri2)[4]  = (int   (*)[4])(smem + 17792);
    int   (*cand)[2] = (int   (*)[2])(smem + 17920);

    for (int base = bid * RPBF; base < n; base += FGRID * RPBF) {
      const int nr = min(RPBF, n - base);
      #pragma unroll
      for (int i = 0; i < 4; ++i) {          // 1024 floats = 8 rows x 128
        int idx = tid + i * 256;
        int r = idx >> 7, k = idx & 127;
        float v = 0.f;
        if (r < nr) v = x[(size_t)list[base + r] * DIM + k];
        xsf[k * RPBF + r] = v;
      }
      __syncthreads();

      f32x4 dot[RPBF];
      #pragma unroll
      for (int r = 0; r < RPBF; ++r) dot[r] = (f32x4){0.f, 0.f, 0.f, 0.f};
      const f32x4* eT4 = (const f32x4*)embedT;
      #pragma unroll 4
      for (int k = 0; k < DIM; ++k) {
        f32x4 e4 = eT4[k * 256 + tid];
        f32x4 xa = *(const f32x4*)&xsf[k * RPBF];
        f32x4 xb = *(const f32x4*)&xsf[k * RPBF + 4];
        #pragma unroll
        for (int r = 0; r < 4; ++r) {
          dot[r][0]   = fmaf(xa[r], e4[0], dot[r][0]);
          dot[r][1]   = fmaf(xa[r], e4[1], dot[r][1]);
          dot[r][2]   = fmaf(xa[r], e4[2], dot[r][2]);
          dot[r][3]   = fmaf(xa[r], e4[3], dot[r][3]);
          dot[r+4][0] = fmaf(xb[r], e4[0], dot[r+4][0]);
          dot[r+4][1] = fmaf(xb[r], e4[1], dot[r+4][1]);
          dot[r+4][2] = fmaf(xb[r], e4[2], dot[r+4][2]);
          dot[r+4][3] = fmaf(xb[r], e4[3], dot[r+4][3]);
        }
      }

      #pragma unroll
      for (int r = 0; r < RPBF; ++r) {
        float b1 = 3.4e38f, b2 = 3.4e38f; int i1 = 0, i2 = 0;
        #pragma unroll
        for (int j = 0; j < 4; ++j) {
          int c = 4 * tid + j;
          float sc = fmaf(-2.0f, dot[r][j], e2f[c]);
          bool better = (sc < b1);
          float lv = better ? b1 : sc;  int li = better ? i1 : c;
          if (better) { b1 = sc; i1 = c; }
          bool t2 = (lv < b2) || (lv == b2 && li < i2);
          if (t2) { b2 = lv; i2 = li; }
        }
        #pragma unroll
        for (int off = 1; off < 64; off <<= 1) {
          float o1 = __shfl_xor(b1, off, 64); int oi1 = __shfl_xor(i1, off, 64);
          float o2 = __shfl_xor(b2, off, 64); int oi2 = __shfl_xor(i2, off, 64);
          bool take = (o1 < b1) || (o1 == b1 && oi1 < i1);
          float n1 = take ? o1 : b1; int ni1 = take ? oi1 : i1;
          float lo = take ? b1 : o1; int loi = take ? i1 : oi1;
          float c2v = take ? o2 : b2; int c2i = take ? oi2 : i2;
          bool u2 = (c2v < lo) || (c2v == lo && c2i < loi);
          b1 = n1; i1 = ni1;
          b2 = u2 ? c2v : lo; i2 = u2 ? c2i : loi;
        }
        if (l == 0) { rb1[r][w] = b1; ri1[r][w] = i1; rb2[r][w] = b2; ri2[r][w] = i2; }
      }
      __syncthreads();

      if (tid < RPBF) {
        float v1 = rb1[tid][0], v2 = rb2[tid][0]; int j1 = ri1[tid][0], j2 = ri2[tid][0];
        #pragma unroll
        for (int ww = 1; ww < 4; ++ww) {
          float o1 = rb1[tid][ww], o2 = rb2[tid][ww]; int oi1 = ri1[tid][ww], oi2 = ri2[tid][ww];
          bool take = (o1 < v1) || (o1 == v1 && oi1 < j1);
          float n1 = take ? o1 : v1; int ni1 = take ? oi1 : j1;
          float lo = take ? v1 : o1; int loi = take ? j1 : oi1;
          float c2v = take ? o2 : v2; int c2i = take ? oi2 : j2;
          bool u2 = (c2v < lo) || (c2v == lo && c2i < loi);
          v1 = n1; j1 = ni1; v2 = u2 ? c2v : lo; j2 = u2 ? c2i : loi;
        }
        cand[tid][0] = j1; cand[tid][1] = j2;
      }
      __syncthreads();

      // f64 rescore: wave w handles rows w and w+4
      #pragma unroll
      for (int rr0 = 0; rr0 < 2; ++rr0) {
        const int rr = w + rr0 * 4;
        if (rr < nr) {
          int c1 = cand[rr][0], c2 = cand[rr][1];
          float xa = xsf[l * RPBF + rr], xb = xsf[(l + 64) * RPBF + rr];
          double p1 = (double)xa * (double)embed[(size_t)c1 * DIM + l]
                    + (double)xb * (double)embed[(size_t)c1 * DIM + 64 + l];
          double p2 = (double)xa * (double)embed[(size_t)c2 * DIM + l]
                    + (double)xb * (double)embed[(size_t)c2 * DIM + 64 + l];
          #pragma unroll
          for (int off = 1; off < 64; off <<= 1) {
            p1 += __shfl_xor(p1, off, 64);
            p2 += __shfl_xor(p2, off, 64);
          }
          double s1 = e2d[c1] - 2.0 * p1;
          double s2 = e2d[c2] - 2.0 * p2;
          int widx = ((s2 < s1) || (s2 == s1 && c2 < c1)) ? c2 : c1;
          int row = list[base + rr];
          if (l == 0) outIdx[row] = (float)widx;
          outQ[(size_t)row * DIM + l]      = embed[(size_t)widx * DIM + l];
          outQ[(size_t)row * DIM + 64 + l] = embed[(size_t)widx * DIM + 64 + l];
        }
      }
      __syncthreads();                       // xsf reused next trip
    }
  }
}

// ==================== FALLBACK (v13 3-launch path) =========================
__global__ __launch_bounds__(256) void setup_kernel(
    const float* __restrict__ embed, double* __restrict__ e2d,
    float* __restrict__ e2f, _Float16* __restrict__ eh,
    float* __restrict__ embedT, int* __restrict__ cnt)
{
  __shared__ float tile[64][132];
  __shared__ double psum[4][64];
  if (blockIdx.x == 0 && threadIdx.x == 0) *cnt = 0;
  const int c0 = blockIdx.x * 64;
  const int t  = threadIdx.x;

  const f32x4* E4 = (const f32x4*)(embed + (size_t)c0 * DIM);
  #pragma unroll
  for (int i = 0; i < 8; ++i) {
    int e = t + i * 256;
    int r = e >> 5, c4 = e & 31;
    f32x4 v = E4[e];
    *(f32x4*)&tile[r][c4 * 4] = v;
    half4 h;
    h[0] = (_Float16)v[0]; h[1] = (_Float16)v[1];
    h[2] = (_Float16)v[2]; h[3] = (_Float16)v[3];
    *(half4*)&eh[(size_t)(c0 + r) * DIM + c4 * 4] = h;
  }
  __syncthreads();
  {
    int r = t & 63, part = t >> 6;
    double s = 0.0;
    #pragma unroll
    for (int k = 0; k < 32; ++k) {
      float v = tile[r][part * 32 + k];
      s += (double)v * v;
    }
    psum[part][r] = s;
  }
  __syncthreads();
  if (t < 64) {
    double s = psum[0][t] + psum[1][t] + psum[2][t] + psum[3][t];
    e2d[c0 + t] = s;
    e2f[c0 + t] = (float)s;
  }
  #pragma unroll
  for (int i = 0; i < 32; ++i) {
    int idx = t + i * 256;
    int k = idx >> 6, c = idx & 63;
    embedT[(size_t)k * NCODES + c0 + c] = tile[c][k];
  }
}

__global__ __launch_bounds__(256, 2) void pass1_kernel(
    const float* __restrict__ x, const float* __restrict__ embed,
    const _Float16* __restrict__ eh, const float* __restrict__ e2f,
    float* __restrict__ outQ, float* __restrict__ outIdx,
    int* __restrict__ cnt, int* __restrict__ list)
{
  __shared__ __align__(16) _Float16 xh[TILE_M * 136];
  __shared__ __align__(16) unsigned char bbuf[4][3][4096];
  __shared__ float rb_best[4][TILE_M];
  __shared__ float rb_sec [4][TILE_M];
  __shared__ int   fidx[TILE_M];

  const int tid  = threadIdx.x;
  const int row0 = blockIdx.x * TILE_M;
  const int l  = tid & 63, w = tid >> 6;
  const int rl = l & 15,  q = l >> 4;

#define STAGE_W(CH)                                                           \
  {                                                                           \
    const char* ebase = (const char*)eh + ((size_t)(CH) * 64 + w * 16) * 256; \
    unsigned char* buf = &bbuf[w][(CH) % 3][0];                               \
    _Pragma("unroll")                                                         \
    for (int j = 0; j < 4; ++j) {                                             \
      int u  = j * 64 + l;                                                    \
      int rr = u >> 4, cc = u & 15;                                           \
      const char* src = ebase + rr * 256 + ((cc ^ rr) * 16);                  \
      __builtin_amdgcn_global_load_lds(                                       \
          (AS1 void*)src,                                                     \
          (AS3 void*)(buf + j * 1024), 16, 0, 0);                             \
    }                                                                         \
  }

  float vin[16];
  #pragma unroll
  for (int g = 0; g < 16; ++g)
    vin[g] = fmaf(-0.5f, e2f[g * 64 + w * 16 + rl], -16.0f);

  {
    const f32x4* x4 = (const f32x4*)(x + (size_t)row0 * DIM);
    #pragma unroll
    for (int i = 0; i < 8; ++i) {
      int e = tid + i * 256;
      int r = e >> 5, c4 = e & 31;
      f32x4 v = x4[e];
      half4 h;
      h[0] = (_Float16)v[0]; h[1] = (_Float16)v[1];
      h[2] = (_Float16)v[2]; h[3] = (_Float16)v[3];
      *(half4*)&xh[r * 136 + c4 * 4] = h;
    }
  }
  __syncthreads();

  half8 afrag[4][4];
  #pragma unroll
  for (int m = 0; m < 4; ++m)
    #pragma unroll
    for (int ks = 0; ks < 4; ++ks)
      afrag[m][ks] = *(const half8*)&xh[(m * 16 + rl) * 136 + ks * 32 + q * 8];

  float bestp[16], secp[16];
  #pragma unroll
  for (int s = 0; s < 16; ++s) { bestp[s] = -3.0e38f; secp[s] = -3.3e38f; }

  STAGE_W(0)
  STAGE_W(1)
  STAGE_W(2)

  #pragma unroll
  for (int ch = 0; ch < 16; ++ch) {
    if (ch <= 13) {
      asm volatile("s_waitcnt vmcnt(8)" ::: "memory");
    } else if (ch == 14) {
      asm volatile("s_waitcnt vmcnt(4)" ::: "memory");
    } else {
      asm volatile("s_waitcnt vmcnt(0)" ::: "memory");
    }
    __builtin_amdgcn_sched_barrier(0);

    const unsigned char* bb = &bbuf[w][ch % 3][0];
    half8 bfrag[4];
    #pragma unroll
    for (int ks = 0; ks < 4; ++ks)
      bfrag[ks] = *(const half8*)(bb + rl * 256 + (((ks * 4 + q) ^ rl) * 16));

    const float vinit = vin[ch];
    const int mycode = ch * 64 + w * 16 + rl;
    #pragma unroll
    for (int m = 0; m < 4; ++m) {
      f32x4 acc = (f32x4){vinit, vinit, vinit, vinit};
      #pragma unroll
      for (int ks = 0; ks < 4; ++ks)
        acc = __builtin_amdgcn_mfma_f32_16x16x32_f16(afrag[m][ks], bfrag[ks], acc, 0, 0, 0);
      #pragma unroll
      for (int r = 0; r < 4; ++r) {
        const int s = m * 4 + r;
        float scp = __int_as_float((__float_as_int(acc[r]) & ~1023) | mycode);
        secp[s]  = __builtin_amdgcn_fmed3f(scp, bestp[s], secp[s]);
        bestp[s] = fmaxf(bestp[s], scp);
      }
    }

    if (ch + 3 < 16) {
      asm volatile("s_waitcnt lgkmcnt(0)" ::: "memory");
      __builtin_amdgcn_sched_barrier(0);
      STAGE_W(ch + 3)
    }
  }
#undef STAGE_W

  #pragma unroll
  for (int off = 1; off < 16; off <<= 1) {
    #pragma unroll
    for (int s = 0; s < 16; ++s) {
      float ob = __shfl_xor(bestp[s], off, 16);
      float os = __shfl_xor(secp[s],  off, 16);
      secp[s]  = fmaxf(__builtin_amdgcn_fmed3f(bestp[s], ob, secp[s]), os);
      bestp[s] = fmaxf(bestp[s], ob);
    }
  }
  if (rl == 0) {
    #pragma unroll
    for (int m = 0; m < 4; ++m)
      #pragma unroll
      for (int r = 0; r < 4; ++r) {
        int s = m * 4 + r;
        int row = m * 16 + q * 4 + r;
        rb_best[w][row] = bestp[s];
        rb_sec [w][row] = secp[s];
      }
  }
  __syncthreads();

  if (tid < TILE_M) {
    float bv = rb_best[0][tid], sv = rb_sec[0][tid];
    #pragma unroll
    for (int ww = 1; ww < 4; ++ww) {
      float ob = rb_best[ww][tid], os = rb_sec[ww][tid];
      sv = fmaxf(__builtin_amdgcn_fmed3f(bv, ob, sv), os);
      bv = fmaxf(bv, ob);
    }
    int bi = __float_as_int(bv) & 1023;
    int grow = row0 + tid;
    outIdx[grow] = (float)bi;
    fidx[tid] = bi;
    if (bv - sv <= FLAGThr) {
      int p = atomicAdd(cnt, 1);
      list[p] = grow;
    }
  }
  __syncthreads();

  {
    const f32x4* E4   = (const f32x4*)embed;
    f32x4*       out4 = (f32x4*)(outQ + (size_t)row0 * DIM);
    #pragma unroll
    for (int i = 0; i < 8; ++i) {
      int e = tid + i * 256;
      int r = e >> 5, c4 = e & 31;
      out4[e] = E4[fidx[r] * 32 + c4];
    }
  }
}

__global__ __launch_bounds__(256) void refine2_kernel(
    const float* __restrict__ x, const float* __restrict__ embed,
    const float* __restrict__ embedT,
    const double* __restrict__ e2d, const float* __restrict__ e2f,
    float* __restrict__ outQ, float* __restrict__ outIdx,
    const int* __restrict__ cnt, const int* __restrict__ list)
{
  __shared__ f32x4 xst[DIM];
  __shared__ float rb1[RPB][4], rb2[RPB][4];
  __shared__ int   ri1[RPB][4], ri2[RPB][4];
  __shared__ int   cand[RPB][2];

  const int t = threadIdx.x;
  const int l = t & 63, w = t >> 6;
  const int n = *cnt;
  float* xsf = (float*)xst;

  for (int base = blockIdx.x * RPB; base < n; base += 1024 * RPB) {
    const int nr = min(RPB, n - base);
    #pragma unroll
    for (int i = 0; i < 2; ++i) {
      int idx = t + i * 256;
      int r = idx >> 7, k = idx & 127;
      float v = 0.f;
      if (r < nr) v = x[(size_t)list[base + r] * DIM + k];
      xsf[k * RPB + r] = v;
    }
    __syncthreads();

    f32x4 dot[RPB];
    #pragma unroll
    for (int r = 0; r < RPB; ++r) dot[r] = (f32x4){0.f, 0.f, 0.f, 0.f};
    const f32x4* eT4 = (const f32x4*)embedT;
    #pragma unroll 4
    for (int k = 0; k < DIM; ++k) {
      f32x4 e4  = eT4[k * 256 + t];
      f32x4 xk4 = xst[k];
      #pragma unroll
      for (int r = 0; r < RPB; ++r) {
        dot[r][0] = fmaf(xk4[r], e4[0], dot[r][0]);
        dot[r][1] = fmaf(xk4[r], e4[1], dot[r][1]);
        dot[r][2] = fmaf(xk4[r], e4[2], dot[r][2]);
        dot[r][3] = fmaf(xk4[r], e4[3], dot[r][3]);
      }
    }

    #pragma unroll
    for (int r = 0; r < RPB; ++r) {
      float b1 = 3.4e38f, b2 = 3.4e38f; int i1 = 0, i2 = 0;
      #pragma unroll
      for (int j = 0; j < 4; ++j) {
        int c = 4 * t + j;
        float sc = fmaf(-2.0f, dot[r][j], e2f[c]);
        bool better = (sc < b1);
        float lv = better ? b1 : sc;  int li = better ? i1 : c;
        if (better) { b1 = sc; i1 = c; }
        bool t2 = (lv < b2) || (lv == b2 && li < i2);
        if (t2) { b2 = lv; i2 = li; }
      }
      #pragma unroll
      for (int off = 1; off < 64; off <<= 1) {
        float o1 = __shfl_xor(b1, off, 64); int oi1 = __shfl_xor(i1, off, 64);
        float o2 = __shfl_xor(b2, off, 64); int oi2 = __shfl_xor(i2, off, 64);
        bool take = (o1 < b1) || (o1 == b1 && oi1 < i1);
        float n1 = take ? o1 : b1; int ni1 = take ? oi1 : i1;
        float lo = take ? b1 : o1; int loi = take ? i1 : oi1;
        float c2v = take ? o2 : b2; int c2i = take ? oi2 : i2;
        bool u2 = (c2v < lo) || (c2v == lo && c2i < loi);
        b1 = n1; i1 = ni1;
        b2 = u2 ? c2v : lo; i2 = u2 ? c2i : loi;
      }
      if (l == 0) { rb1[r][w] = b1; ri1[r][w] = i1; rb2[r][w] = b2; ri2[r][w] = i2; }
    }
    __syncthreads();

    if (t < RPB) {
      float v1 = rb1[t][0], v2 = rb2[t][0]; int j1 = ri1[t][0], j2 = ri2[t][0];
      #pragma unroll
      for (int ww = 1; ww < 4; ++ww) {
        float o1 = rb1[t][ww], o2 = rb2[t][ww]; int oi1 = ri1[t][ww], oi2 = ri2[t][ww];
        bool take = (o1 < v1) || (o1 == v1 && oi1 < j1);
        float n1 = take ? o1 : v1; int ni1 = take ? oi1 : j1;
        float lo = take ? v1 : o1; int loi = take ? j1 : oi1;
        float c2v = take ? o2 : v2; int c2i = take ? oi2 : j2;
        bool u2 = (c2v < lo) || (c2v == lo && c2i < loi);
        v1 = n1; j1 = ni1; v2 = u2 ? c2v : lo; j2 = u2 ? c2i : loi;
      }
      cand[t][0] = j1; cand[t][1] = j2;
    }
    __syncthreads();

    if (w < nr) {
      int c1 = cand[w][0], c2 = cand[w][1];
      float xa = xsf[l * RPB + w], xb = xsf[(l + 64) * RPB + w];
      double p1 = (double)xa * (double)embed[(size_t)c1 * DIM + l]
                + (double)xb * (double)embed[(size_t)c1 * DIM + 64 + l];
      double p2 = (double)xa * (double)embed[(size_t)c2 * DIM + l]
                + (double)xb * (double)embed[(size_t)c2 * DIM + 64 + l];
      #pragma unroll
      for (int off = 1; off < 64; off <<= 1) {
        p1 += __shfl_xor(p1, off, 64);
        p2 += __shfl_xor(p2, off, 64);
      }
      double s1 = e2d[c1] - 2.0 * p1;
      double s2 = e2d[c2] - 2.0 * p2;
      int widx = ((s2 < s1) || (s2 == s1 && c2 < c1)) ? c2 : c1;
      int row = list[base + w];
      if (l == 0) outIdx[row] = (float)widx;
      outQ[(size_t)row * DIM + l]      = embed[(size_t)widx * DIM + l];
      outQ[(size_t)row * DIM + 64 + l] = embed[(size_t)widx * DIM + 64 + l];
    }
    __syncthreads();
  }
}

extern "C" void kernel_launch(void* const* d_in, const int* in_sizes, int n_in,
                              void* d_out, int out_size, void* d_ws, size_t ws_size,
                              hipStream_t stream) {
  const float* x     = (const float*)d_in[0];
  const float* embed = (const float*)d_in[1];
  const int N = in_sizes[0] / DIM;             // 65536 rows

  float* out    = (float*)d_out;
  float* outQ   = out;                         // [N*128] quantize
  float* outIdx = out + (size_t)N * DIM;       // [N] indices as float

  char* ws = (char*)d_ws;
  double*   e2d  = (double*)  (ws);
  float*    e2f  = (float*)   (ws + 8192);
  _Float16* eh   = (_Float16*)(ws + 12288);
  float*    eT   = (float*)   (ws + 274432);
  int*      cnt  = (int*)     (ws + 798720);
  int*      list = (int*)     (ws + 798976);

  void* args[] = { (void*)&x, (void*)&embed, (void*)&e2d, (void*)&e2f,
                   (void*)&eh, (void*)&eT, (void*)&outQ, (void*)&outIdx,
                   (void*)&cnt, (void*)&list };
  hipError_t err = hipLaunchCooperativeKernel((const void*)fused_kernel,
                                              dim3(FGRID), dim3(256),
                                              args, 0, stream);
  if (err != hipSuccess) {
    // fallback: proven v13 3-launch path
    setup_kernel  <<<NCODES / 64, 256, 0, stream>>>(embed, e2d, e2f, eh, eT, cnt);
    pass1_kernel  <<<N / TILE_M,  256, 0, stream>>>(x, embed, eh, e2f, outQ, outIdx, cnt, list);
    refine2_kernel<<<1024,        256, 0, stream>>>(x, embed, eT, e2d, e2f, outQ, outIdx, cnt, list);
  }
}

// Round 12
// 139.723 us; speedup vs baseline: 2.2931x; 2.2931x over previous
//
#include <hip/hip_runtime.h>

#define DIM     128
#define NCODES  1024
#define TILE_M  64
#define FLAGThr 0.018f       // acc-units: fp16 Hoeffding 0.010 + 2x pack err 0.008
#define RPB     8            // refine rows per block (v14-verified logic)
#define RGRID   512          // refine grid

typedef __attribute__((ext_vector_type(8))) _Float16 half8;
typedef __attribute__((ext_vector_type(4))) _Float16 half4;
typedef __attribute__((ext_vector_type(4))) float    f32x4;

#define AS1 __attribute__((address_space(1)))
#define AS3 __attribute__((address_space(3)))

// ws layout:
//      0 : e2d    (1024 double)          8 KB
//   8192 : e2f    (1024 float)           4 KB
//  12288 : eh     (1024*128 _Float16)  256 KB
// 274432 : embedT (128*1024 float)     512 KB
// 798720 : cnt    (int)
// 798976 : list   (65536 int)          256 KB

// -------- setup v2: 64 blocks x 16 codes (4x parallelism vs 16x64) --------
// r11: fusion failed (spill + 2 blocks/CU for all phases); revert to
// 3-launch. setup was 16 blocks = 6% occupancy, latency/write-bound ->
// quadruple block count. Same math: e2 f32/f64, eh fp16, embedT transpose.
__global__ __launch_bounds__(256) void setup_kernel(
    const float* __restrict__ embed, double* __restrict__ e2d,
    float* __restrict__ e2f, _Float16* __restrict__ eh,
    float* __restrict__ embedT, int* __restrict__ cnt)
{
  __shared__ float tile[16][132];            // 132: 16B-aligned rows
  __shared__ double psum[4][16];
  if (blockIdx.x == 0 && threadIdx.x == 0) *cnt = 0;
  const int c0 = blockIdx.x * 16;            // 64 blocks x 16 codes
  const int t  = threadIdx.x;

  const f32x4* E4 = (const f32x4*)(embed + (size_t)c0 * DIM);
  #pragma unroll
  for (int i = 0; i < 2; ++i) {
    int e = t + i * 256;                     // 512 float4s = 16x128
    int r = e >> 5, c4 = e & 31;
    f32x4 v = E4[e];
    *(f32x4*)&tile[r][c4 * 4] = v;
    half4 h;
    h[0] = (_Float16)v[0]; h[1] = (_Float16)v[1];
    h[2] = (_Float16)v[2]; h[3] = (_Float16)v[3];
    *(half4*)&eh[(size_t)(c0 + r) * DIM + c4 * 4] = h;
  }
  __syncthreads();

  // e2: 4 threads per code, 32 dims each (threads 0..63)
  if (t < 64) {
    int r = t & 15, part = t >> 4;
    double s = 0.0;
    #pragma unroll
    for (int k = 0; k < 32; ++k) {
      float v = tile[r][part * 32 + k];
      s += (double)v * v;
    }
    psum[part][r] = s;
  }
  __syncthreads();
  if (t < 16) {
    double s = psum[0][t] + psum[1][t] + psum[2][t] + psum[3][t];
    e2d[c0 + t] = s;
    e2f[c0 + t] = (float)s;
  }

  // embedT[k][c0+c] = tile[c][k]; 64B segments per k-row (16 floats)
  #pragma unroll
  for (int i = 0; i < 8; ++i) {
    int idx = t + i * 256;                   // 2048 = 128k x 16c
    int k = idx >> 4, c = idx & 15;
    embedT[(size_t)k * NCODES + c0 + c] = tile[c][k];
  }
}

// -------- pass1 v13 (unchanged): depth-3 wave-private DMA, uncapped regs ---
// acc = x.e - 0.5*e2 - 16 (init in MFMA C); argmax(acc) == argmin dist.
// Index in low 10 mantissa bits; rows with top-2 gap <= FLAGThr re-decided
// exactly by refine2. Proven clean: FETCH 20.7/WRITE 33.1 MB, VGPR 96,
// 44.7us. Wave-private 3-deep gload_lds pipeline, counted vmcnt (never
// drain mid-loop), zero main-loop barriers, swizzle involution
// (src col cc^rr at stage, read col (ks*4+q)^rl).
__global__ __launch_bounds__(256, 2) void pass1_kernel(
    const float* __restrict__ x, const float* __restrict__ embed,
    const _Float16* __restrict__ eh, const float* __restrict__ e2f,
    float* __restrict__ outQ, float* __restrict__ outIdx,
    int* __restrict__ cnt, int* __restrict__ list)
{
  __shared__ __align__(16) _Float16 xh[TILE_M * 136];
  __shared__ __align__(16) unsigned char bbuf[4][3][4096];
  __shared__ float rb_best[4][TILE_M];
  __shared__ float rb_sec [4][TILE_M];
  __shared__ int   fidx[TILE_M];

  const int tid  = threadIdx.x;
  const int row0 = blockIdx.x * TILE_M;
  const int l  = tid & 63, w = tid >> 6;
  const int rl = l & 15,  q = l >> 4;

#define STAGE_W(CH)                                                           \
  {                                                                           \
    const char* ebase = (const char*)eh + ((size_t)(CH) * 64 + w * 16) * 256; \
    unsigned char* buf = &bbuf[w][(CH) % 3][0];                               \
    _Pragma("unroll")                                                         \
    for (int j = 0; j < 4; ++j) {                                             \
      int u  = j * 64 + l;                                                    \
      int rr = u >> 4, cc = u & 15;                                           \
      const char* src = ebase + rr * 256 + ((cc ^ rr) * 16);                  \
      __builtin_amdgcn_global_load_lds(                                       \
          (AS1 void*)src,                                                     \
          (AS3 void*)(buf + j * 1024), 16, 0, 0);                             \
    }                                                                         \
  }

  float vin[16];                             // code(ch) = ch*64 + w*16 + rl
  #pragma unroll
  for (int g = 0; g < 16; ++g)
    vin[g] = fmaf(-0.5f, e2f[g * 64 + w * 16 + rl], -16.0f);

  {
    const f32x4* x4 = (const f32x4*)(x + (size_t)row0 * DIM);
    #pragma unroll
    for (int i = 0; i < 8; ++i) {
      int e = tid + i * 256;
      int r = e >> 5, c4 = e & 31;
      f32x4 v = x4[e];
      half4 h;
      h[0] = (_Float16)v[0]; h[1] = (_Float16)v[1];
      h[2] = (_Float16)v[2]; h[3] = (_Float16)v[3];
      *(half4*)&xh[r * 136 + c4 * 4] = h;
    }
  }
  __syncthreads();

  half8 afrag[4][4];
  #pragma unroll
  for (int m = 0; m < 4; ++m)
    #pragma unroll
    for (int ks = 0; ks < 4; ++ks)
      afrag[m][ks] = *(const half8*)&xh[(m * 16 + rl) * 136 + ks * 32 + q * 8];

  float bestp[16], secp[16];
  #pragma unroll
  for (int s = 0; s < 16; ++s) { bestp[s] = -3.0e38f; secp[s] = -3.3e38f; }

  STAGE_W(0)
  STAGE_W(1)
  STAGE_W(2)

  #pragma unroll
  for (int ch = 0; ch < 16; ++ch) {
    if (ch <= 13) {
      asm volatile("s_waitcnt vmcnt(8)" ::: "memory");
    } else if (ch == 14) {
      asm volatile("s_waitcnt vmcnt(4)" ::: "memory");
    } else {
      asm volatile("s_waitcnt vmcnt(0)" ::: "memory");
    }
    __builtin_amdgcn_sched_barrier(0);

    const unsigned char* bb = &bbuf[w][ch % 3][0];
    half8 bfrag[4];
    #pragma unroll
    for (int ks = 0; ks < 4; ++ks)
      bfrag[ks] = *(const half8*)(bb + rl * 256 + (((ks * 4 + q) ^ rl) * 16));

    const float vinit = vin[ch];
    const int mycode = ch * 64 + w * 16 + rl;
    #pragma unroll
    for (int m = 0; m < 4; ++m) {
      f32x4 acc = (f32x4){vinit, vinit, vinit, vinit};
      #pragma unroll
      for (int ks = 0; ks < 4; ++ks)
        acc = __builtin_amdgcn_mfma_f32_16x16x32_f16(afrag[m][ks], bfrag[ks], acc, 0, 0, 0);
      #pragma unroll
      for (int r = 0; r < 4; ++r) {
        const int s = m * 4 + r;
        float scp = __int_as_float((__float_as_int(acc[r]) & ~1023) | mycode);
        secp[s]  = __builtin_amdgcn_fmed3f(scp, bestp[s], secp[s]);
        bestp[s] = fmaxf(bestp[s], scp);
      }
    }

    if (ch + 3 < 16) {
      asm volatile("s_waitcnt lgkmcnt(0)" ::: "memory");
      __builtin_amdgcn_sched_barrier(0);
      STAGE_W(ch + 3)
    }
  }
#undef STAGE_W

  #pragma unroll
  for (int off = 1; off < 16; off <<= 1) {
    #pragma unroll
    for (int s = 0; s < 16; ++s) {
      float ob = __shfl_xor(bestp[s], off, 16);
      float os = __shfl_xor(secp[s],  off, 16);
      secp[s]  = fmaxf(__builtin_amdgcn_fmed3f(bestp[s], ob, secp[s]), os);
      bestp[s] = fmaxf(bestp[s], ob);
    }
  }
  if (rl == 0) {
    #pragma unroll
    for (int m = 0; m < 4; ++m)
      #pragma unroll
      for (int r = 0; r < 4; ++r) {
        int s = m * 4 + r;
        int row = m * 16 + q * 4 + r;
        rb_best[w][row] = bestp[s];
        rb_sec [w][row] = secp[s];
      }
  }
  __syncthreads();

  if (tid < TILE_M) {
    float bv = rb_best[0][tid], sv = rb_sec[0][tid];
    #pragma unroll
    for (int ww = 1; ww < 4; ++ww) {
      float ob = rb_best[ww][tid], os = rb_sec[ww][tid];
      sv = fmaxf(__builtin_amdgcn_fmed3f(bv, ob, sv), os);
      bv = fmaxf(bv, ob);
    }
    int bi = __float_as_int(bv) & 1023;
    int grow = row0 + tid;
    outIdx[grow] = (float)bi;
    fidx[tid] = bi;
    if (bv - sv <= FLAGThr) {
      int p = atomicAdd(cnt, 1);
      list[p] = grow;
    }
  }
  __syncthreads();

  {
    const f32x4* E4   = (const f32x4*)embed;
    f32x4*       out4 = (f32x4*)(outQ + (size_t)row0 * DIM);
    #pragma unroll
    for (int i = 0; i < 8; ++i) {
      int e = tid + i * 256;
      int r = e >> 5, c4 = e & 31;
      out4[e] = E4[fidx[r] * 32 + c4];
    }
  }
}

// -------- refine v3: RPB=8 @ 512 blocks (v14-phase2-verified logic) --------
// Halves the per-flagged-row embedT streaming vs RPB=4 @ 1024: each block
// sweeps the 512KB embedT once per 8 rows. f64 rescore: wave w rows w,w+4.
__global__ __launch_bounds__(256) void refine2_kernel(
    const float* __restrict__ x, const float* __restrict__ embed,
    const float* __restrict__ embedT,
    const double* __restrict__ e2d, const float* __restrict__ e2f,
    float* __restrict__ outQ, float* __restrict__ outIdx,
    const int* __restrict__ cnt, const int* __restrict__ list)
{
  __shared__ float xsf[DIM * RPB];           // xsf[k*8+r]: dim k of row r (4KB)
  __shared__ float rb1[RPB][4], rb2[RPB][4];
  __shared__ int   ri1[RPB][4], ri2[RPB][4];
  __shared__ int   cand[RPB][2];

  const int t = threadIdx.x;
  const int l = t & 63, w = t >> 6;
  const int n = *cnt;

  for (int base = blockIdx.x * RPB; base < n; base += RGRID * RPB) {
    const int nr = min(RPB, n - base);
    #pragma unroll
    for (int i = 0; i < 4; ++i) {            // 1024 floats = 8 rows x 128
      int idx = t + i * 256;
      int r = idx >> 7, k = idx & 127;
      float v = 0.f;
      if (r < nr) v = x[(size_t)list[base + r] * DIM + k];
      xsf[k * RPB + r] = v;
    }
    __syncthreads();

    f32x4 dot[RPB];
    #pragma unroll
    for (int r = 0; r < RPB; ++r) dot[r] = (f32x4){0.f, 0.f, 0.f, 0.f};
    const f32x4* eT4 = (const f32x4*)embedT;
    #pragma unroll 4
    for (int k = 0; k < DIM; ++k) {
      f32x4 e4 = eT4[k * 256 + t];
      f32x4 xa = *(const f32x4*)&xsf[k * RPB];
      f32x4 xb = *(const f32x4*)&xsf[k * RPB + 4];
      #pragma unroll
      for (int r = 0; r < 4; ++r) {
        dot[r][0]   = fmaf(xa[r], e4[0], dot[r][0]);
        dot[r][1]   = fmaf(xa[r], e4[1], dot[r][1]);
        dot[r][2]   = fmaf(xa[r], e4[2], dot[r][2]);
        dot[r][3]   = fmaf(xa[r], e4[3], dot[r][3]);
        dot[r+4][0] = fmaf(xb[r], e4[0], dot[r+4][0]);
        dot[r+4][1] = fmaf(xb[r], e4[1], dot[r+4][1]);
        dot[r+4][2] = fmaf(xb[r], e4[2], dot[r+4][2]);
        dot[r+4][3] = fmaf(xb[r], e4[3], dot[r+4][3]);
      }
    }

    #pragma unroll
    for (int r = 0; r < RPB; ++r) {
      float b1 = 3.4e38f, b2 = 3.4e38f; int i1 = 0, i2 = 0;
      #pragma unroll
      for (int j = 0; j < 4; ++j) {
        int c = 4 * t + j;
        float sc = fmaf(-2.0f, dot[r][j], e2f[c]);
        bool better = (sc < b1);                 // ties keep lower index
        float lv = better ? b1 : sc;  int li = better ? i1 : c;
        if (better) { b1 = sc; i1 = c; }
        bool t2 = (lv < b2) || (lv == b2 && li < i2);
        if (t2) { b2 = lv; i2 = li; }
      }
      #pragma unroll
      for (int off = 1; off < 64; off <<= 1) {
        float o1 = __shfl_xor(b1, off, 64); int oi1 = __shfl_xor(i1, off, 64);
        float o2 = __shfl_xor(b2, off, 64); int oi2 = __shfl_xor(i2, off, 64);
        bool take = (o1 < b1) || (o1 == b1 && oi1 < i1);
        float n1 = take ? o1 : b1; int ni1 = take ? oi1 : i1;
        float lo = take ? b1 : o1; int loi = take ? i1 : oi1;
        float c2v = take ? o2 : b2; int c2i = take ? oi2 : i2;
        bool u2 = (c2v < lo) || (c2v == lo && c2i < loi);
        b1 = n1; i1 = ni1;
        b2 = u2 ? c2v : lo; i2 = u2 ? c2i : loi;
      }
      if (l == 0) { rb1[r][w] = b1; ri1[r][w] = i1; rb2[r][w] = b2; ri2[r][w] = i2; }
    }
    __syncthreads();

    if (t < RPB) {
      float v1 = rb1[t][0], v2 = rb2[t][0]; int j1 = ri1[t][0], j2 = ri2[t][0];
      #pragma unroll
      for (int ww = 1; ww < 4; ++ww) {
        float o1 = rb1[t][ww], o2 = rb2[t][ww]; int oi1 = ri1[t][ww], oi2 = ri2[t][ww];
        bool take = (o1 < v1) || (o1 == v1 && oi1 < j1);
        float n1 = take ? o1 : v1; int ni1 = take ? oi1 : j1;
        float lo = take ? v1 : o1; int loi = take ? j1 : oi1;
        float c2v = take ? o2 : v2; int c2i = take ? oi2 : j2;
        bool u2 = (c2v < lo) || (c2v == lo && c2i < loi);
        v1 = n1; j1 = ni1; v2 = u2 ? c2v : lo; j2 = u2 ? c2i : loi;
      }
      cand[t][0] = j1; cand[t][1] = j2;
    }
    __syncthreads();

    // f64 rescore: wave w handles rows w and w+4
    #pragma unroll
    for (int rr0 = 0; rr0 < 2; ++rr0) {
      const int rr = w + rr0 * 4;
      if (rr < nr) {
        int c1 = cand[rr][0], c2 = cand[rr][1];
        float xa = xsf[l * RPB + rr], xb = xsf[(l + 64) * RPB + rr];
        double p1 = (double)xa * (double)embed[(size_t)c1 * DIM + l]
                  + (double)xb * (double)embed[(size_t)c1 * DIM + 64 + l];
        double p2 = (double)xa * (double)embed[(size_t)c2 * DIM + l]
                  + (double)xb * (double)embed[(size_t)c2 * DIM + 64 + l];
        #pragma unroll
        for (int off = 1; off < 64; off <<= 1) {
          p1 += __shfl_xor(p1, off, 64);
          p2 += __shfl_xor(p2, off, 64);
        }
        double s1 = e2d[c1] - 2.0 * p1;
        double s2 = e2d[c2] - 2.0 * p2;
        int widx = ((s2 < s1) || (s2 == s1 && c2 < c1)) ? c2 : c1;
        int row = list[base + rr];
        if (l == 0) outIdx[row] = (float)widx;
        outQ[(size_t)row * DIM + l]      = embed[(size_t)widx * DIM + l];
        outQ[(size_t)row * DIM + 64 + l] = embed[(size_t)widx * DIM + 64 + l];
      }
    }
    __syncthreads();   // xsf reused next trip
  }
}

extern "C" void kernel_launch(void* const* d_in, const int* in_sizes, int n_in,
                              void* d_out, int out_size, void* d_ws, size_t ws_size,
                              hipStream_t stream) {
  const float* x     = (const float*)d_in[0];
  const float* embed = (const float*)d_in[1];
  const int N = in_sizes[0] / DIM;             // 65536 rows

  float* out    = (float*)d_out;
  float* outQ   = out;                         // [N*128] quantize
  float* outIdx = out + (size_t)N * DIM;       // [N] indices as float

  char* ws = (char*)d_ws;
  double*   e2d  = (double*)  (ws);
  float*    e2f  = (float*)   (ws + 8192);
  _Float16* eh   = (_Float16*)(ws + 12288);
  float*    eT   = (float*)   (ws + 274432);
  int*      cnt  = (int*)     (ws + 798720);
  int*      list = (int*)     (ws + 798976);

  setup_kernel  <<<NCODES / 16, 256, 0, stream>>>(embed, e2d, e2f, eh, eT, cnt);
  pass1_kernel  <<<N / TILE_M,  256, 0, stream>>>(x, embed, eh, e2f, outQ, outIdx, cnt, list);
  refine2_kernel<<<RGRID,       256, 0, stream>>>(x, embed, eT, e2d, e2f, outQ, outIdx, cnt, list);
}